// Round 3
// baseline (592.154 us; speedup 1.0000x reference)
//
#include <hip/hip_runtime.h>

// FMoELinearProj — R5: drop the split-K P buffer + reduce4. gemm2 now
// atomicAdds its K-quarter contribution directly into out (zero-initialized
// by a small fill kernel). Saves ~110 MiB HBM vs R4. GEMM template unchanged
// (256x256xBK=64 8-phase, A bf16 GLL16 + B fp32 reg-staged/cvt_pk, counted
// vmcnt gates, raw s_barrier, setprio).
// ws layout: Xb 16MiB @0, Y 64MiB @16Mi. NEED=80MiB.

#define NEXP 16
#define TTOK 8192
#define DIN  1024
#define DOUT 4096
#define SDIM 512
#define LDSS 40   // fallback-path LDS stride

typedef short short8 __attribute__((ext_vector_type(8)));
typedef float floatx4 __attribute__((ext_vector_type(4)));
typedef unsigned short ushort_t;

__device__ __forceinline__ ushort_t f2bf(float f) {
    union { float f; unsigned u; } v; v.f = f;
    unsigned r = v.u + 0x7FFFu + ((v.u >> 16) & 1u);   // RNE
    return (ushort_t)(r >> 16);
}

__device__ __forceinline__ unsigned cvtpk(float lo, float hi) {
    unsigned r;
    asm("v_cvt_pk_bf16_f32 %0, %1, %2" : "=v"(r) : "v"(lo), "v"(hi));
    return r;
}

#define GLL16(g, l) __builtin_amdgcn_global_load_lds( \
    (const __attribute__((address_space(1))) void*)(g), \
    (__attribute__((address_space(3))) void*)(l), 16, 0, 0)

// ---------------- fp32 -> bf16 streaming convert (X only) ----------------
__global__ __launch_bounds__(256)
void cvt_kernel(const float* __restrict__ src, ushort_t* __restrict__ dst, int n8) {
    const int i = blockIdx.x * 256 + threadIdx.x;
    if (i >= n8) return;
    const float4 a = ((const float4*)src)[2 * i];
    const float4 b = ((const float4*)src)[2 * i + 1];
    short8 o;
    o[0] = (short)f2bf(a.x); o[1] = (short)f2bf(a.y);
    o[2] = (short)f2bf(a.z); o[3] = (short)f2bf(a.w);
    o[4] = (short)f2bf(b.x); o[5] = (short)f2bf(b.y);
    o[6] = (short)f2bf(b.z); o[7] = (short)f2bf(b.w);
    ((short8*)dst)[i] = o;
}

// ---------------- zero-init out (gemm2 accumulates atomically) ----------------
__global__ __launch_bounds__(256)
void zero_kernel(float* __restrict__ dst) {
    const int i = blockIdx.x * 256 + threadIdx.x;   // float4 index
    ((float4*)dst)[i] = make_float4(0.f, 0.f, 0.f, 0.f);
}

// ============== 8-phase 256x256 GEMM, BK=64 (A bf16 GLL16, B fp32 reg-staged) =====
// 8 waves = 2(M) x 4(N); per-wave 128x64 out; acc[8][4]; LDS 2x(A 32K + B 32K).
// Per tile t: P1{rdB-all+rdA m01 | GLL16 A'(q0,q1) | vmcnt(6) | write B'(q0,q1)}
//             P2{rdA m23 | GLL16 A'(q2,q3) | vmcnt(4) | write B'(q2,q3)}
//             P3{rdA m45 | load B''(q0,q1)}  P4{rdA m67 | load B''(q2,q3) | vmcnt(8)}
// each phase: lgkmcnt(0) (publish ds_writes), barrier, setprio+16 MFMA, barrier.
// FIFO ledger (per tile: 2G,2G,4L,4L): gates drain exactly the quarters being
// consumed; 8-12 vmem ops always in flight, never drained to 0 in the loop.
// G1: epilogue adds bias, writes bf16 Y. !G1: epilogue atomicAdds fp32 to out.
template<bool G1>
__global__ __launch_bounds__(512, 2)
void gemm8p(const ushort_t* __restrict__ Ain, const int* __restrict__ counts,
            const float* __restrict__ Bf, const float* __restrict__ bias,
            ushort_t* __restrict__ Yout, float* __restrict__ Pout) {
    __shared__ __align__(16) ushort_t As[2 * 16384];
    __shared__ __align__(16) ushort_t Bs[2 * 16384];

    int e, mt, nt, kq;
    if constexpr (G1) {
        // 512 blocks -> 8 XCDs x 64 slots (2 experts/XCD); m fastest (W-tile share)
        const int l = ((blockIdx.x & 7) << 6) | (blockIdx.x >> 3);
        e = l >> 5; nt = (l >> 1) & 15; mt = l & 1; kq = 0;
    } else {
        // 256 blocks -> 8 XCDs x 32 slots; m fastest, split-K=4
        const int l = ((blockIdx.x & 7) << 5) | (blockIdx.x >> 3);
        e = l >> 4; kq = (l >> 2) & 3; nt = (l >> 1) & 1; mt = l & 1;
    }
    const int LDK = G1 ? DIN : DOUT;   // k-stride for both A (bf16) and B (fp32)

    int off = 0;
    for (int i = 0; i < e; ++i) off += counts[i];
    const int cnt = counts[e];

    const int tid = threadIdx.x, wave = tid >> 6, lane = tid & 63;
    const int wm = wave >> 2, wn = wave & 3;
    const int l15 = lane & 15, quad = lane >> 4;
    const int srow = (wave << 3) + (lane >> 3);            // row within a 64-row quarter
    const int swz8 = ((lane & 7) ^ (lane >> 3)) << 3;      // granule swizzle (elems)
    const int aseg = off + (mt << 8);

    // A row base pointers (bf16, source-side swizzle so linear GLL16 dest works)
    const ushort_t* ap[4];
    #pragma unroll
    for (int q = 0; q < 4; ++q) {
        int r = aseg + (q << 6) + srow; if (r >= TTOK) r = TTOK - 1;
        ap[q] = Ain + (size_t)r * LDK + (G1 ? 0 : (kq << 10)) + swz8;
    }
    // B row base pointers (fp32, linear source; swizzle applied on ds_write)
    const float* bpq[4];
    {
        const float* Bbase = G1
            ? (Bf + (size_t)e * DOUT * DIN  + ((size_t)(nt << 8)) * DIN)
            : (Bf + (size_t)e * SDIM * DOUT + ((size_t)(nt << 8)) * DOUT + (kq << 10));
        #pragma unroll
        for (int q = 0; q < 4; ++q)
            bpq[q] = Bbase + (size_t)((q << 6) + srow) * LDK + ((lane & 7) << 3);
    }
    const int aLdsW  = (wave << 9);             // + (q<<12) + buf
    const int bWrOff = (srow << 6) + swz8;      // + (q<<12) + buf

    auto rdA = [&](int bufe, int m, int s) -> short8 {
        return *(const short8*)&As[bufe + ((wm << 7) + (m << 4) + l15) * 64
                                   + ((((s << 2) | quad) ^ (lane & 7)) << 3)];
    };
    auto rdB = [&](int bufe, int n, int s) -> short8 {
        return *(const short8*)&Bs[bufe + ((wn << 6) + (n << 4) + l15) * 64
                                   + ((((s << 2) | quad) ^ (lane & 7)) << 3)];
    };

    floatx4 acc[8][4] = {};
    short8 bfv[4][2], af0[2], af1[2];
    float4 bq[4][2];

#define GA(NB, q, kt) GLL16(ap[q] + ((kt) << 6), As + (NB) + ((q) << 12) + aLdsW)
#define LB(q, kt) { const float* _p = bpq[q] + ((kt) << 6); \
    bq[q][0] = *(const float4*)_p; bq[q][1] = *(const float4*)(_p + 4); }
#define WRB(NB, q) { uint4 _w; \
    _w.x = cvtpk(bq[q][0].x, bq[q][0].y); _w.y = cvtpk(bq[q][0].z, bq[q][0].w); \
    _w.z = cvtpk(bq[q][1].x, bq[q][1].y); _w.w = cvtpk(bq[q][1].z, bq[q][1].w); \
    *(uint4*)&Bs[(NB) + ((q) << 12) + bWrOff] = _w; }
#define RDB_ALL(BUFE) { _Pragma("unroll") \
    for (int n = 0; n < 4; ++n) { bfv[n][0] = rdB(BUFE,n,0); bfv[n][1] = rdB(BUFE,n,1); } }
#define RDA2(BUFE, M0) { af0[0]=rdA(BUFE,M0,0); af0[1]=rdA(BUFE,M0,1); \
                         af1[0]=rdA(BUFE,(M0)+1,0); af1[1]=rdA(BUFE,(M0)+1,1); }
#define MFMA16(M0) { \
    __builtin_amdgcn_s_setprio(1); \
    _Pragma("unroll") for (int n = 0; n < 4; ++n) { \
      acc[M0][n]     = __builtin_amdgcn_mfma_f32_16x16x32_bf16(af0[0], bfv[n][0], acc[M0][n],     0,0,0); \
      acc[M0][n]     = __builtin_amdgcn_mfma_f32_16x16x32_bf16(af0[1], bfv[n][1], acc[M0][n],     0,0,0); \
      acc[(M0)+1][n] = __builtin_amdgcn_mfma_f32_16x16x32_bf16(af1[0], bfv[n][0], acc[(M0)+1][n], 0,0,0); \
      acc[(M0)+1][n] = __builtin_amdgcn_mfma_f32_16x16x32_bf16(af1[1], bfv[n][1], acc[(M0)+1][n], 0,0,0); } \
    __builtin_amdgcn_s_setprio(0); }
#define VMC(N) asm volatile("s_waitcnt vmcnt(" #N ")" ::: "memory")
#define LGKM0  asm volatile("s_waitcnt lgkmcnt(0)" ::: "memory")
#define BAR()  __builtin_amdgcn_s_barrier()

#define TILE(BUF, NBUF, KA, KB) { \
    RDB_ALL(BUF); RDA2(BUF, 0); \
    GA(NBUF, 0, KA); GA(NBUF, 1, KA); \
    VMC(6); WRB(NBUF, 0); WRB(NBUF, 1); \
    LGKM0; BAR(); MFMA16(0); BAR(); \
    RDA2(BUF, 2); \
    GA(NBUF, 2, KA); GA(NBUF, 3, KA); \
    VMC(4); WRB(NBUF, 2); WRB(NBUF, 3); \
    LGKM0; BAR(); MFMA16(2); BAR(); \
    RDA2(BUF, 4); \
    LB(0, KB); LB(1, KB); \
    BAR(); MFMA16(4); BAR(); \
    RDA2(BUF, 6); \
    LB(2, KB); LB(3, KB); \
    VMC(8); \
    BAR(); MFMA16(6); BAR(); }

    // ---- prologue: B(0) load+write, A(0) GLL16, B(1) load; prime FIFO = 8 ----
    LB(0, 0); LB(1, 0); LB(2, 0); LB(3, 0);
    GA(0, 0, 0); GA(0, 1, 0); GA(0, 2, 0); GA(0, 3, 0);
    VMC(4);
    WRB(0, 0); WRB(0, 1); WRB(0, 2); WRB(0, 3);
    LB(0, 1); LB(1, 1); LB(2, 1); LB(3, 1);
    VMC(8);
    LGKM0; BAR();

    #pragma unroll 1
    for (int it = 0; it < 8; ++it) {
        const int ka0 = 2 * it + 1;
        const int kb0 = (it < 7) ? 2 * it + 2 : 15;   // clamped dummies keep counts uniform
        const int kb1 = (it < 7) ? 2 * it + 3 : 15;
        TILE(0, 16384, ka0, kb0);       // tile 2it   (buf0): stage A(2it+1), load B(2it+2)
        TILE(16384, 0, kb0, kb1);       // tile 2it+1 (buf1): stage A(2it+2), load B(2it+3)
    }

#undef TILE
#undef GA
#undef LB
#undef WRB
#undef RDB_ALL
#undef RDA2
#undef MFMA16
#undef VMC
#undef LGKM0
#undef BAR

    // ---- epilogue ----
    if constexpr (G1) {
        float bv[4];
        #pragma unroll
        for (int n = 0; n < 4; ++n)
            bv[n] = bias[e * DOUT + (nt << 8) + (wn << 6) + (n << 4) + l15];
        #pragma unroll
        for (int m = 0; m < 8; ++m) {
            #pragma unroll
            for (int rg = 0; rg < 4; ++rg) {
                const int trow = (mt << 8) + (wm << 7) + (m << 4) + (quad << 2) + rg;
                if (trow < cnt) {
                    ushort_t* yp = Yout + (size_t)(off + trow) * DOUT + (nt << 8) + (wn << 6);
                    #pragma unroll
                    for (int n = 0; n < 4; ++n)
                        yp[(n << 4) + l15] = f2bf(acc[m][n][rg] + bv[n]);
                }
            }
        }
    } else {
        #pragma unroll
        for (int m = 0; m < 8; ++m) {
            #pragma unroll
            for (int rg = 0; rg < 4; ++rg) {
                const int trow = (mt << 8) + (wm << 7) + (m << 4) + (quad << 2) + rg;
                if (trow < cnt) {
                    float* op = Pout + (size_t)(off + trow) * SDIM + (nt << 8) + (wn << 6);
                    #pragma unroll
                    for (int n = 0; n < 4; ++n)
                        atomicAdd(&op[(n << 4) + l15], acc[m][n][rg]);
                }
            }
        }
    }
}

// ================= fallback (R1, correct, ws >= 64 MiB) =================
__global__ __launch_bounds__(256, 2)
void gemm1_o(const float* __restrict__ X, const int* __restrict__ counts,
             const float* __restrict__ W, const float* __restrict__ bias,
             ushort_t* __restrict__ Y) {
    __shared__ __align__(16) ushort_t As[128 * LDSS];
    __shared__ __align__(16) ushort_t Bs[128 * LDSS];
    const int bid = blockIdx.x;
    const int e = bid >> 7, r_ = bid & 127;
    const int n_tile = r_ >> 2, m_tile = r_ & 3;
    int off = 0;
    for (int i = 0; i < e; ++i) off += counts[i];
    const int cnt = counts[e];
    const int t = threadIdx.x, wave = t >> 6, lane = t & 63;
    const int wm = (wave & 1) << 6, wn = (wave >> 1) << 6;
    const int l15 = lane & 15, quad = lane >> 4;
    const float* Wp = W + (size_t)e * DOUT * DIN + (size_t)(n_tile << 7) * DIN;
    floatx4 acc[4][4] = {};
    const int srow = t >> 3, scol = (t & 7) << 2;
    for (int k0 = 0; k0 < DIN; k0 += 32) {
        #pragma unroll
        for (int p = 0; p < 4; ++p) {
            const int row = srow + (p << 5);
            int grow = off + (m_tile << 7) + row;
            if (grow >= TTOK) grow = 0;
            const float4 v = *(const float4*)(X + (size_t)grow * DIN + k0 + scol);
            unsigned lo = (unsigned)f2bf(v.x) | ((unsigned)f2bf(v.y) << 16);
            unsigned hi = (unsigned)f2bf(v.z) | ((unsigned)f2bf(v.w) << 16);
            *(uint2*)&As[row * LDSS + scol] = make_uint2(lo, hi);
        }
        #pragma unroll
        for (int p = 0; p < 4; ++p) {
            const int row = srow + (p << 5);
            const float4 v = *(const float4*)(Wp + (size_t)row * DIN + k0 + scol);
            unsigned lo = (unsigned)f2bf(v.x) | ((unsigned)f2bf(v.y) << 16);
            unsigned hi = (unsigned)f2bf(v.z) | ((unsigned)f2bf(v.w) << 16);
            *(uint2*)&Bs[row * LDSS + scol] = make_uint2(lo, hi);
        }
        __syncthreads();
        short8 af[4], bfr[4];
        #pragma unroll
        for (int i = 0; i < 4; ++i) {
            af[i]  = *(const short8*)&As[(wm + (i << 4) + l15) * LDSS + (quad << 3)];
            bfr[i] = *(const short8*)&Bs[(wn + (i << 4) + l15) * LDSS + (quad << 3)];
        }
        #pragma unroll
        for (int mi = 0; mi < 4; ++mi)
            #pragma unroll
            for (int ni = 0; ni < 4; ++ni)
                acc[mi][ni] = __builtin_amdgcn_mfma_f32_16x16x32_bf16(
                    af[mi], bfr[ni], acc[mi][ni], 0, 0, 0);
        __syncthreads();
    }
    float bv[4];
    #pragma unroll
    for (int ni = 0; ni < 4; ++ni)
        bv[ni] = bias[e * DOUT + (n_tile << 7) + wn + (ni << 4) + l15];
    #pragma unroll
    for (int mi = 0; mi < 4; ++mi)
        #pragma unroll
        for (int rg = 0; rg < 4; ++rg) {
            const int trow = (m_tile << 7) + wm + (mi << 4) + (quad << 2) + rg;
            if (trow < cnt) {
                ushort_t* yp = Y + (size_t)(off + trow) * DOUT + (n_tile << 7) + wn;
                #pragma unroll
                for (int ni = 0; ni < 4; ++ni)
                    yp[(ni << 4) + l15] = f2bf(acc[mi][ni][rg] + bv[ni]);
            }
        }
}

__global__ __launch_bounds__(256, 2)
void gemm2_o(const ushort_t* __restrict__ Y, const int* __restrict__ counts,
             const float* __restrict__ C, float* __restrict__ O) {
    __shared__ __align__(16) ushort_t As[128 * LDSS];
    __shared__ __align__(16) ushort_t Bs[128 * LDSS];
    const int bid = blockIdx.x;
    const int e = bid >> 4, r_ = bid & 15;
    const int n_tile = r_ >> 2, m_tile = r_ & 3;
    int off = 0;
    for (int i = 0; i < e; ++i) off += counts[i];
    const int cnt = counts[e];
    const int t = threadIdx.x, wave = t >> 6, lane = t & 63;
    const int wm = (wave & 1) << 6, wn = (wave >> 1) << 6;
    const int l15 = lane & 15, quad = lane >> 4;
    const float* Cp = C + (size_t)e * SDIM * DOUT + (size_t)(n_tile << 7) * DOUT;
    floatx4 acc[4][4] = {};
    const int arow = t >> 2, achk = (t & 3) << 3;
    const int srow = t >> 3, scol = (t & 7) << 2;
    for (int k0 = 0; k0 < DOUT; k0 += 32) {
        #pragma unroll
        for (int p = 0; p < 2; ++p) {
            const int row = arow + (p << 6);
            int grow = off + (m_tile << 7) + row;
            if (grow >= TTOK) grow = 0;
            const short8 v = *(const short8*)(Y + (size_t)grow * DOUT + k0 + achk);
            *(short8*)&As[row * LDSS + achk] = v;
        }
        #pragma unroll
        for (int p = 0; p < 4; ++p) {
            const int row = srow + (p << 5);
            const float4 v = *(const float4*)(Cp + (size_t)row * DOUT + k0 + scol);
            unsigned lo = (unsigned)f2bf(v.x) | ((unsigned)f2bf(v.y) << 16);
            unsigned hi = (unsigned)f2bf(v.z) | ((unsigned)f2bf(v.w) << 16);
            *(uint2*)&Bs[row * LDSS + scol] = make_uint2(lo, hi);
        }
        __syncthreads();
        short8 af[4], bfr[4];
        #pragma unroll
        for (int i = 0; i < 4; ++i) {
            af[i]  = *(const short8*)&As[(wm + (i << 4) + l15) * LDSS + (quad << 3)];
            bfr[i] = *(const short8*)&Bs[(wn + (i << 4) + l15) * LDSS + (quad << 3)];
        }
        #pragma unroll
        for (int mi = 0; mi < 4; ++mi)
            #pragma unroll
            for (int ni = 0; ni < 4; ++ni)
                acc[mi][ni] = __builtin_amdgcn_mfma_f32_16x16x32_bf16(
                    af[mi], bfr[ni], acc[mi][ni], 0, 0, 0);
        __syncthreads();
    }
    #pragma unroll
    for (int mi = 0; mi < 4; ++mi)
        #pragma unroll
        for (int rg = 0; rg < 4; ++rg) {
            const int trow = (m_tile << 7) + wm + (mi << 4) + (quad << 2) + rg;
            if (trow < cnt) {
                float* op = O + (size_t)(off + trow) * SDIM + (n_tile << 7) + wn;
                #pragma unroll
                for (int ni = 0; ni < 4; ++ni)
                    op[(ni << 4) + l15] = acc[mi][ni][rg];
            }
        }
}

extern "C" void kernel_launch(void* const* d_in, const int* in_sizes, int n_in,
                              void* d_out, int out_size, void* d_ws, size_t ws_size,
                              hipStream_t stream) {
    const float* X      = (const float*)d_in[0];
    const int*   counts = (const int*)d_in[1];
    const float* W      = (const float*)d_in[2];
    const float* bias   = (const float*)d_in[3];
    const float* comp   = (const float*)d_in[4];
    float* out = (float*)d_out;

    const size_t OFF_XB = 0;            // 16 MiB bf16 X
    const size_t OFF_Y  = 16777216;     // 64 MiB bf16 Y
    const size_t NEED   = 83886080;     // 80 MiB total

    if (ws_size >= NEED) {
        ushort_t* Xb = (ushort_t*)((char*)d_ws + OFF_XB);
        ushort_t* Y  = (ushort_t*)((char*)d_ws + OFF_Y);

        zero_kernel<<<dim3(4096), dim3(256), 0, stream>>>(out);   // out = 16 MiB = 4096*256 float4
        cvt_kernel<<<dim3(4096), dim3(256), 0, stream>>>(X, Xb, 1048576);
        gemm8p<true><<<dim3(512),  dim3(512), 0, stream>>>(Xb, counts, W, bias, Y, nullptr);
        gemm8p<false><<<dim3(256), dim3(512), 0, stream>>>(Y, counts, comp, nullptr, nullptr, out);
    } else {
        ushort_t* Y = (ushort_t*)d_ws;   // 64 MiB
        gemm1_o<<<dim3(2048), dim3(256), 0, stream>>>(X, counts, W, bias, Y);
        gemm2_o<<<dim3(256),  dim3(256), 0, stream>>>(Y, counts, comp, out);
    }
}

// Round 4
// 571.767 us; speedup vs baseline: 1.0357x; 1.0357x over previous
//
#include <hip/hip_runtime.h>

// FMoELinearProj — R6: revert R5's atomics (regressed +26 µs; device-scope
// atomicAdd ~50 µs slower than P+reduce). gemm2 reworked: split-K=2 with
// 256x128 tile (256 blocks, full fill), P = 32 MiB fp32 + reduce2.
// Same 8-phase counted-vmcnt schedule; B-LDS 16 KiB/buf; uniform VMC(4).
// gemm1 unchanged from R4 (256x256, A bf16 GLL16, B=W fp32 reg-staged).
// ws: Xb 16MiB @0, Y 64MiB @16Mi, P 32MiB @80Mi. NEED=112MiB.

#define NEXP 16
#define TTOK 8192
#define DIN  1024
#define DOUT 4096
#define SDIM 512
#define LDSS 40   // fallback-path LDS stride

typedef short short8 __attribute__((ext_vector_type(8)));
typedef float floatx4 __attribute__((ext_vector_type(4)));
typedef unsigned short ushort_t;

__device__ __forceinline__ ushort_t f2bf(float f) {
    union { float f; unsigned u; } v; v.f = f;
    unsigned r = v.u + 0x7FFFu + ((v.u >> 16) & 1u);   // RNE
    return (ushort_t)(r >> 16);
}

__device__ __forceinline__ unsigned cvtpk(float lo, float hi) {
    unsigned r;
    asm("v_cvt_pk_bf16_f32 %0, %1, %2" : "=v"(r) : "v"(lo), "v"(hi));
    return r;
}

#define GLL16(g, l) __builtin_amdgcn_global_load_lds( \
    (const __attribute__((address_space(1))) void*)(g), \
    (__attribute__((address_space(3))) void*)(l), 16, 0, 0)

// ---------------- fp32 -> bf16 streaming convert (X only) ----------------
__global__ __launch_bounds__(256)
void cvt_kernel(const float* __restrict__ src, ushort_t* __restrict__ dst, int n8) {
    const int i = blockIdx.x * 256 + threadIdx.x;
    if (i >= n8) return;
    const float4 a = ((const float4*)src)[2 * i];
    const float4 b = ((const float4*)src)[2 * i + 1];
    short8 o;
    o[0] = (short)f2bf(a.x); o[1] = (short)f2bf(a.y);
    o[2] = (short)f2bf(a.z); o[3] = (short)f2bf(a.w);
    o[4] = (short)f2bf(b.x); o[5] = (short)f2bf(b.y);
    o[6] = (short)f2bf(b.z); o[7] = (short)f2bf(b.w);
    ((short8*)dst)[i] = o;
}

// ---------------- shared schedule macros ----------------
#define VMC(N) asm volatile("s_waitcnt vmcnt(" #N ")" ::: "memory")
#define LGKM0  asm volatile("s_waitcnt lgkmcnt(0)" ::: "memory")
#define BAR()  __builtin_amdgcn_s_barrier()

// ============ GEMM1: 256x256xBK=64 8-phase (A=Xb bf16 GLL16, B=W fp32) ============
__global__ __launch_bounds__(512, 2)
void gemm1_8p(const ushort_t* __restrict__ Ain, const int* __restrict__ counts,
              const float* __restrict__ Bf, const float* __restrict__ bias,
              ushort_t* __restrict__ Yout) {
    __shared__ __align__(16) ushort_t As[2 * 16384];
    __shared__ __align__(16) ushort_t Bs[2 * 16384];

    // 512 blocks -> 8 XCDs x 64 slots (2 experts/XCD); m fastest (W-tile share)
    const int l = ((blockIdx.x & 7) << 6) | (blockIdx.x >> 3);
    const int e = l >> 5;
    const int nt = (l >> 1) & 15, mt = l & 1;

    int off = 0;
    for (int i = 0; i < e; ++i) off += counts[i];
    const int cnt = counts[e];

    const int tid = threadIdx.x, wave = tid >> 6, lane = tid & 63;
    const int wm = wave >> 2, wn = wave & 3;
    const int l15 = lane & 15, quad = lane >> 4;
    const int srow = (wave << 3) + (lane >> 3);
    const int swz8 = ((lane & 7) ^ (lane >> 3)) << 3;
    const int aseg = off + (mt << 8);

    const ushort_t* ap[4];
    #pragma unroll
    for (int q = 0; q < 4; ++q) {
        int r = aseg + (q << 6) + srow; if (r >= TTOK) r = TTOK - 1;
        ap[q] = Ain + (size_t)r * DIN + swz8;
    }
    const float* bpq[4];
    {
        const float* Bbase = Bf + (size_t)e * DOUT * DIN + ((size_t)(nt << 8)) * DIN;
        #pragma unroll
        for (int q = 0; q < 4; ++q)
            bpq[q] = Bbase + (size_t)((q << 6) + srow) * DIN + ((lane & 7) << 3);
    }
    const int aLdsW  = (wave << 9);
    const int bWrOff = (srow << 6) + swz8;

    auto rdA = [&](int bufe, int m, int s) -> short8 {
        return *(const short8*)&As[bufe + ((wm << 7) + (m << 4) + l15) * 64
                                   + ((((s << 2) | quad) ^ (lane & 7)) << 3)];
    };
    auto rdB = [&](int bufe, int n, int s) -> short8 {
        return *(const short8*)&Bs[bufe + ((wn << 6) + (n << 4) + l15) * 64
                                   + ((((s << 2) | quad) ^ (lane & 7)) << 3)];
    };

    floatx4 acc[8][4] = {};
    short8 bfv[4][2], af0[2], af1[2];
    float4 bq[4][2];

#define GA(NB, q, kt) GLL16(ap[q] + ((kt) << 6), As + (NB) + ((q) << 12) + aLdsW)
#define LB(q, kt) { const float* _p = bpq[q] + ((kt) << 6); \
    bq[q][0] = *(const float4*)_p; bq[q][1] = *(const float4*)(_p + 4); }
#define WRB(NB, q) { uint4 _w; \
    _w.x = cvtpk(bq[q][0].x, bq[q][0].y); _w.y = cvtpk(bq[q][0].z, bq[q][0].w); \
    _w.z = cvtpk(bq[q][1].x, bq[q][1].y); _w.w = cvtpk(bq[q][1].z, bq[q][1].w); \
    *(uint4*)&Bs[(NB) + ((q) << 12) + bWrOff] = _w; }
#define RDB_ALL(BUFE) { _Pragma("unroll") \
    for (int n = 0; n < 4; ++n) { bfv[n][0] = rdB(BUFE,n,0); bfv[n][1] = rdB(BUFE,n,1); } }
#define RDA2(BUFE, M0) { af0[0]=rdA(BUFE,M0,0); af0[1]=rdA(BUFE,M0,1); \
                         af1[0]=rdA(BUFE,(M0)+1,0); af1[1]=rdA(BUFE,(M0)+1,1); }
#define MFMA16(M0) { \
    __builtin_amdgcn_s_setprio(1); \
    _Pragma("unroll") for (int n = 0; n < 4; ++n) { \
      acc[M0][n]     = __builtin_amdgcn_mfma_f32_16x16x32_bf16(af0[0], bfv[n][0], acc[M0][n],     0,0,0); \
      acc[M0][n]     = __builtin_amdgcn_mfma_f32_16x16x32_bf16(af0[1], bfv[n][1], acc[M0][n],     0,0,0); \
      acc[(M0)+1][n] = __builtin_amdgcn_mfma_f32_16x16x32_bf16(af1[0], bfv[n][0], acc[(M0)+1][n], 0,0,0); \
      acc[(M0)+1][n] = __builtin_amdgcn_mfma_f32_16x16x32_bf16(af1[1], bfv[n][1], acc[(M0)+1][n], 0,0,0); } \
    __builtin_amdgcn_s_setprio(0); }

#define TILE1(BUF, NBUF, KA, KB) { \
    RDB_ALL(BUF); RDA2(BUF, 0); \
    GA(NBUF, 0, KA); GA(NBUF, 1, KA); \
    VMC(6); WRB(NBUF, 0); WRB(NBUF, 1); \
    LGKM0; BAR(); MFMA16(0); BAR(); \
    RDA2(BUF, 2); \
    GA(NBUF, 2, KA); GA(NBUF, 3, KA); \
    VMC(4); WRB(NBUF, 2); WRB(NBUF, 3); \
    LGKM0; BAR(); MFMA16(2); BAR(); \
    RDA2(BUF, 4); \
    LB(0, KB); LB(1, KB); \
    BAR(); MFMA16(4); BAR(); \
    RDA2(BUF, 6); \
    LB(2, KB); LB(3, KB); \
    VMC(8); \
    BAR(); MFMA16(6); BAR(); }

    // prologue: B(0) load+write, A(0) GLL16, B(1) load; prime FIFO = 8
    LB(0, 0); LB(1, 0); LB(2, 0); LB(3, 0);
    GA(0, 0, 0); GA(0, 1, 0); GA(0, 2, 0); GA(0, 3, 0);
    VMC(4);
    WRB(0, 0); WRB(0, 1); WRB(0, 2); WRB(0, 3);
    LB(0, 1); LB(1, 1); LB(2, 1); LB(3, 1);
    VMC(8);
    LGKM0; BAR();

    #pragma unroll 1
    for (int it = 0; it < 8; ++it) {
        const int ka0 = 2 * it + 1;
        const int kb0 = (it < 7) ? 2 * it + 2 : 15;
        const int kb1 = (it < 7) ? 2 * it + 3 : 15;
        TILE1(0, 16384, ka0, kb0);
        TILE1(16384, 0, kb0, kb1);
    }
    asm volatile("s_waitcnt vmcnt(0)" ::: "memory");

#undef TILE1
#undef GA
#undef LB
#undef WRB
#undef RDB_ALL
#undef RDA2
#undef MFMA16

    float bv[4];
    #pragma unroll
    for (int n = 0; n < 4; ++n)
        bv[n] = bias[e * DOUT + (nt << 8) + (wn << 6) + (n << 4) + l15];
    #pragma unroll
    for (int m = 0; m < 8; ++m) {
        #pragma unroll
        for (int rg = 0; rg < 4; ++rg) {
            const int trow = (mt << 8) + (wm << 7) + (m << 4) + (quad << 2) + rg;
            if (trow < cnt) {
                ushort_t* yp = Yout + (size_t)(off + trow) * DOUT + (nt << 8) + (wn << 6);
                #pragma unroll
                for (int n = 0; n < 4; ++n)
                    yp[(n << 4) + l15] = f2bf(acc[m][n][rg] + bv[n]);
            }
        }
    }
}

// ============ GEMM2: 256x128xBK=64 8-phase, split-K=2 (A=Y bf16 GLL16, B=comp fp32) ====
// 256 blocks: e(16) x kq(2) x nt(4) x mt(2), m fastest. Per block K-half = 2048
// -> 32 K-tiles. B-LDS 128x64 bf16 = 16 KiB/buf, staged in 2 halves (64 rows).
// Ops/phase = 2 (P1/P2: GA pairs; P3/P4: LB halves); uniform VMC(4) at P1/P2/P4.
__global__ __launch_bounds__(512, 2)
void gemm2_8p(const ushort_t* __restrict__ Yin, const int* __restrict__ counts,
              const float* __restrict__ comp, float* __restrict__ P) {
    __shared__ __align__(16) ushort_t As[2 * 16384];
    __shared__ __align__(16) ushort_t Bs[2 * 8192];

    const int l = ((blockIdx.x & 7) << 5) | (blockIdx.x >> 3);
    const int e = l >> 4;
    const int r = l & 15;
    const int mt = r & 1, nt2 = (r >> 1) & 3, kq = r >> 3;

    int off = 0;
    for (int i = 0; i < e; ++i) off += counts[i];
    const int cnt = counts[e];

    const int tid = threadIdx.x, wave = tid >> 6, lane = tid & 63;
    const int wm = wave >> 2, wn = wave & 3;
    const int l15 = lane & 15, quad = lane >> 4;
    const int srow = (wave << 3) + (lane >> 3);
    const int swz8 = ((lane & 7) ^ (lane >> 3)) << 3;

    const ushort_t* ap[4];
    #pragma unroll
    for (int q = 0; q < 4; ++q) {
        int rr = off + (mt << 8) + (q << 6) + srow; if (rr >= TTOK) rr = TTOK - 1;
        ap[q] = Yin + (size_t)rr * DOUT + (kq << 11) + swz8;
    }
    const float* bph[2];
    {
        const float* Bbase = comp + (size_t)e * SDIM * DOUT
                           + ((size_t)(nt2 << 7)) * DOUT + (kq << 11);
        #pragma unroll
        for (int h = 0; h < 2; ++h)
            bph[h] = Bbase + (size_t)((h << 6) + srow) * DOUT + ((lane & 7) << 3);
    }
    const int aLdsW  = (wave << 9);
    const int bWrOff = (srow << 6) + swz8;

    auto rdA = [&](int bufe, int m, int s) -> short8 {
        return *(const short8*)&As[bufe + ((wm << 7) + (m << 4) + l15) * 64
                                   + ((((s << 2) | quad) ^ (lane & 7)) << 3)];
    };
    auto rdB = [&](int bufe, int n, int s) -> short8 {
        return *(const short8*)&Bs[bufe + ((wn << 5) + (n << 4) + l15) * 64
                                   + ((((s << 2) | quad) ^ (lane & 7)) << 3)];
    };

    floatx4 acc[8][2] = {};
    short8 bfv[2][2], af0[2], af1[2];
    float4 bq[2][2];

#define GA2(AB, q, kt) GLL16(ap[q] + ((kt) << 6), As + (AB) + ((q) << 12) + aLdsW)
#define LB2(h, kt) { const float* _p = bph[h] + ((kt) << 6); \
    bq[h][0] = *(const float4*)_p; bq[h][1] = *(const float4*)(_p + 4); }
#define WRB2(BB, h) { uint4 _w; \
    _w.x = cvtpk(bq[h][0].x, bq[h][0].y); _w.y = cvtpk(bq[h][0].z, bq[h][0].w); \
    _w.z = cvtpk(bq[h][1].x, bq[h][1].y); _w.w = cvtpk(bq[h][1].z, bq[h][1].w); \
    *(uint4*)&Bs[(BB) + ((h) << 12) + bWrOff] = _w; }
#define RDB_ALL2(BB) { _Pragma("unroll") \
    for (int n = 0; n < 2; ++n) { bfv[n][0] = rdB(BB,n,0); bfv[n][1] = rdB(BB,n,1); } }
#define RDA2(AB, M0) { af0[0]=rdA(AB,M0,0); af0[1]=rdA(AB,M0,1); \
                       af1[0]=rdA(AB,(M0)+1,0); af1[1]=rdA(AB,(M0)+1,1); }
#define MFMA8(M0) { \
    __builtin_amdgcn_s_setprio(1); \
    _Pragma("unroll") for (int n = 0; n < 2; ++n) { \
      acc[M0][n]     = __builtin_amdgcn_mfma_f32_16x16x32_bf16(af0[0], bfv[n][0], acc[M0][n],     0,0,0); \
      acc[M0][n]     = __builtin_amdgcn_mfma_f32_16x16x32_bf16(af0[1], bfv[n][1], acc[M0][n],     0,0,0); \
      acc[(M0)+1][n] = __builtin_amdgcn_mfma_f32_16x16x32_bf16(af1[0], bfv[n][0], acc[(M0)+1][n], 0,0,0); \
      acc[(M0)+1][n] = __builtin_amdgcn_mfma_f32_16x16x32_bf16(af1[1], bfv[n][1], acc[(M0)+1][n], 0,0,0); } \
    __builtin_amdgcn_s_setprio(0); }

#define TILE2(AB, BB, NAB, NBB, KA, KB) { \
    RDB_ALL2(BB); RDA2(AB, 0); \
    GA2(NAB, 0, KA); GA2(NAB, 1, KA); \
    VMC(4); WRB2(NBB, 0); \
    LGKM0; BAR(); MFMA8(0); BAR(); \
    RDA2(AB, 2); \
    GA2(NAB, 2, KA); GA2(NAB, 3, KA); \
    VMC(4); WRB2(NBB, 1); \
    LGKM0; BAR(); MFMA8(2); BAR(); \
    RDA2(AB, 4); \
    LB2(0, KB); \
    BAR(); MFMA8(4); BAR(); \
    RDA2(AB, 6); \
    LB2(1, KB); \
    VMC(4); \
    BAR(); MFMA8(6); BAR(); }

    // prologue: prime FIFO = 4 (next tile's B-half loads)
    LB2(0, 0); LB2(1, 0);
    GA2(0, 0, 0); GA2(0, 1, 0); GA2(0, 2, 0); GA2(0, 3, 0);
    VMC(4);
    WRB2(0, 0); WRB2(0, 1);
    LB2(0, 1); LB2(1, 1);
    VMC(4);
    LGKM0; BAR();

    #pragma unroll 1
    for (int it = 0; it < 16; ++it) {
        const int ka0 = 2 * it + 1;
        const int kb0 = (it < 15) ? 2 * it + 2 : 31;
        const int kb1 = (it < 15) ? 2 * it + 3 : 31;
        TILE2(0, 0, 16384, 8192, ka0, kb0);
        TILE2(16384, 8192, 0, 0, kb0, kb1);
    }
    asm volatile("s_waitcnt vmcnt(0)" ::: "memory");

#undef TILE2
#undef GA2
#undef LB2
#undef WRB2
#undef RDB_ALL2
#undef RDA2
#undef MFMA8

    float* pp = P + (size_t)kq * ((size_t)TTOK * SDIM);
    #pragma unroll
    for (int m = 0; m < 8; ++m) {
        #pragma unroll
        for (int rg = 0; rg < 4; ++rg) {
            const int trow = (mt << 8) + (wm << 7) + (m << 4) + (quad << 2) + rg;
            if (trow < cnt) {
                float* op = pp + (size_t)(off + trow) * SDIM + (nt2 << 7) + (wn << 5);
                #pragma unroll
                for (int n = 0; n < 2; ++n)
                    op[(n << 4) + l15] = acc[m][n][rg];
            }
        }
    }
}

__global__ __launch_bounds__(256)
void reduce2_kernel(const float* __restrict__ P, float* __restrict__ O) {
    const int i = blockIdx.x * 256 + threadIdx.x;   // float4 index
    const size_t S = (size_t)TTOK * SDIM;
    const float4 a = ((const float4*)P)[i];
    const float4 b = ((const float4*)(P + S))[i];
    ((float4*)O)[i] = make_float4(a.x + b.x, a.y + b.y, a.z + b.z, a.w + b.w);
}

// ================= fallback (R1, correct, ws >= 64 MiB) =================
__global__ __launch_bounds__(256, 2)
void gemm1_o(const float* __restrict__ X, const int* __restrict__ counts,
             const float* __restrict__ W, const float* __restrict__ bias,
             ushort_t* __restrict__ Y) {
    __shared__ __align__(16) ushort_t As[128 * LDSS];
    __shared__ __align__(16) ushort_t Bs[128 * LDSS];
    const int bid = blockIdx.x;
    const int e = bid >> 7, r_ = bid & 127;
    const int n_tile = r_ >> 2, m_tile = r_ & 3;
    int off = 0;
    for (int i = 0; i < e; ++i) off += counts[i];
    const int cnt = counts[e];
    const int t = threadIdx.x, wave = t >> 6, lane = t & 63;
    const int wm = (wave & 1) << 6, wn = (wave >> 1) << 6;
    const int l15 = lane & 15, quad = lane >> 4;
    const float* Wp = W + (size_t)e * DOUT * DIN + (size_t)(n_tile << 7) * DIN;
    floatx4 acc[4][4] = {};
    const int srow = t >> 3, scol = (t & 7) << 2;
    for (int k0 = 0; k0 < DIN; k0 += 32) {
        #pragma unroll
        for (int p = 0; p < 4; ++p) {
            const int row = srow + (p << 5);
            int grow = off + (m_tile << 7) + row;
            if (grow >= TTOK) grow = 0;
            const float4 v = *(const float4*)(X + (size_t)grow * DIN + k0 + scol);
            unsigned lo = (unsigned)f2bf(v.x) | ((unsigned)f2bf(v.y) << 16);
            unsigned hi = (unsigned)f2bf(v.z) | ((unsigned)f2bf(v.w) << 16);
            *(uint2*)&As[row * LDSS + scol] = make_uint2(lo, hi);
        }
        #pragma unroll
        for (int p = 0; p < 4; ++p) {
            const int row = srow + (p << 5);
            const float4 v = *(const float4*)(Wp + (size_t)row * DIN + k0 + scol);
            unsigned lo = (unsigned)f2bf(v.x) | ((unsigned)f2bf(v.y) << 16);
            unsigned hi = (unsigned)f2bf(v.z) | ((unsigned)f2bf(v.w) << 16);
            *(uint2*)&Bs[row * LDSS + scol] = make_uint2(lo, hi);
        }
        __syncthreads();
        short8 af[4], bfr[4];
        #pragma unroll
        for (int i = 0; i < 4; ++i) {
            af[i]  = *(const short8*)&As[(wm + (i << 4) + l15) * LDSS + (quad << 3)];
            bfr[i] = *(const short8*)&Bs[(wn + (i << 4) + l15) * LDSS + (quad << 3)];
        }
        #pragma unroll
        for (int mi = 0; mi < 4; ++mi)
            #pragma unroll
            for (int ni = 0; ni < 4; ++ni)
                acc[mi][ni] = __builtin_amdgcn_mfma_f32_16x16x32_bf16(
                    af[mi], bfr[ni], acc[mi][ni], 0, 0, 0);
        __syncthreads();
    }
    float bv[4];
    #pragma unroll
    for (int ni = 0; ni < 4; ++ni)
        bv[ni] = bias[e * DOUT + (n_tile << 7) + wn + (ni << 4) + l15];
    #pragma unroll
    for (int mi = 0; mi < 4; ++mi)
        #pragma unroll
        for (int rg = 0; rg < 4; ++rg) {
            const int trow = (m_tile << 7) + wm + (mi << 4) + (quad << 2) + rg;
            if (trow < cnt) {
                ushort_t* yp = Y + (size_t)(off + trow) * DOUT + (n_tile << 7) + wn;
                #pragma unroll
                for (int ni = 0; ni < 4; ++ni)
                    yp[(ni << 4) + l15] = f2bf(acc[mi][ni][rg] + bv[ni]);
            }
        }
}

__global__ __launch_bounds__(256, 2)
void gemm2_o(const ushort_t* __restrict__ Y, const int* __restrict__ counts,
             const float* __restrict__ C, float* __restrict__ O) {
    __shared__ __align__(16) ushort_t As[128 * LDSS];
    __shared__ __align__(16) ushort_t Bs[128 * LDSS];
    const int bid = blockIdx.x;
    const int e = bid >> 4, r_ = bid & 15;
    const int n_tile = r_ >> 2, m_tile = r_ & 3;
    int off = 0;
    for (int i = 0; i < e; ++i) off += counts[i];
    const int cnt = counts[e];
    const int t = threadIdx.x, wave = t >> 6, lane = t & 63;
    const int wm = (wave & 1) << 6, wn = (wave >> 1) << 6;
    const int l15 = lane & 15, quad = lane >> 4;
    const float* Cp = C + (size_t)e * SDIM * DOUT + (size_t)(n_tile << 7) * DOUT;
    floatx4 acc[4][4] = {};
    const int arow = t >> 2, achk = (t & 3) << 3;
    const int srow = t >> 3, scol = (t & 7) << 2;
    for (int k0 = 0; k0 < DOUT; k0 += 32) {
        #pragma unroll
        for (int p = 0; p < 2; ++p) {
            const int row = arow + (p << 6);
            int grow = off + (m_tile << 7) + row;
            if (grow >= TTOK) grow = 0;
            const short8 v = *(const short8*)(Y + (size_t)grow * DOUT + k0 + achk);
            *(short8*)&As[row * LDSS + achk] = v;
        }
        #pragma unroll
        for (int p = 0; p < 4; ++p) {
            const int row = srow + (p << 5);
            const float4 v = *(const float4*)(Cp + (size_t)row * DOUT + k0 + scol);
            unsigned lo = (unsigned)f2bf(v.x) | ((unsigned)f2bf(v.y) << 16);
            unsigned hi = (unsigned)f2bf(v.z) | ((unsigned)f2bf(v.w) << 16);
            *(uint2*)&Bs[row * LDSS + scol] = make_uint2(lo, hi);
        }
        __syncthreads();
        short8 af[4], bfr[4];
        #pragma unroll
        for (int i = 0; i < 4; ++i) {
            af[i]  = *(const short8*)&As[(wm + (i << 4) + l15) * LDSS + (quad << 3)];
            bfr[i] = *(const short8*)&Bs[(wn + (i << 4) + l15) * LDSS + (quad << 3)];
        }
        #pragma unroll
        for (int mi = 0; mi < 4; ++mi)
            #pragma unroll
            for (int ni = 0; ni < 4; ++ni)
                acc[mi][ni] = __builtin_amdgcn_mfma_f32_16x16x32_bf16(
                    af[mi], bfr[ni], acc[mi][ni], 0, 0, 0);
        __syncthreads();
    }
    #pragma unroll
    for (int mi = 0; mi < 4; ++mi)
        #pragma unroll
        for (int rg = 0; rg < 4; ++rg) {
            const int trow = (m_tile << 7) + wm + (mi << 4) + (quad << 2) + rg;
            if (trow < cnt) {
                float* op = O + (size_t)(off + trow) * SDIM + (n_tile << 7) + wn;
                #pragma unroll
                for (int ni = 0; ni < 4; ++ni)
                    op[(ni << 4) + l15] = acc[mi][ni][rg];
            }
        }
}

extern "C" void kernel_launch(void* const* d_in, const int* in_sizes, int n_in,
                              void* d_out, int out_size, void* d_ws, size_t ws_size,
                              hipStream_t stream) {
    const float* X      = (const float*)d_in[0];
    const int*   counts = (const int*)d_in[1];
    const float* W      = (const float*)d_in[2];
    const float* bias   = (const float*)d_in[3];
    const float* comp   = (const float*)d_in[4];
    float* out = (float*)d_out;

    const size_t OFF_XB = 0;            // 16 MiB bf16 X
    const size_t OFF_Y  = 16777216;     // 64 MiB bf16 Y
    const size_t OFF_P  = 83886080;     // 32 MiB fp32 P (split-K=2 partials)
    const size_t NEED   = 117440512;    // 112 MiB total

    if (ws_size >= NEED) {
        ushort_t* Xb = (ushort_t*)((char*)d_ws + OFF_XB);
        ushort_t* Y  = (ushort_t*)((char*)d_ws + OFF_Y);
        float*    P  = (float*)((char*)d_ws + OFF_P);

        cvt_kernel<<<dim3(4096), dim3(256), 0, stream>>>(X, Xb, 1048576);
        gemm1_8p<<<dim3(512), dim3(512), 0, stream>>>(Xb, counts, W, bias, Y);
        gemm2_8p<<<dim3(256), dim3(512), 0, stream>>>(Y, counts, comp, P);
        reduce2_kernel<<<dim3(4096), dim3(256), 0, stream>>>(P, out);
    } else {
        ushort_t* Y = (ushort_t*)d_ws;   // 64 MiB
        gemm1_o<<<dim3(2048), dim3(256), 0, stream>>>(X, counts, W, bias, Y);
        gemm2_o<<<dim3(256),  dim3(256), 0, stream>>>(Y, counts, comp, out);
    }
}